// Round 3
// baseline (167.642 us; speedup 1.0000x reference)
//
#include <hip/hip_runtime.h>
#include <math.h>

#define NROWS 32
#define TLEN  64000
#define NH    60
#define CPR   250                 // 256-elem chunks per row (64000/256)
#define NCHUNK (NROWS * CPR)      // 8000

// Phase is computed in float64: a parallel f64 scan matches the f64 golden
// reference to ~1e-13 rad (no bit-matching constraint), which removes the
// sequential dependency chain entirely.

__device__ inline double phase_inc(float f0v) {
    // golden (np float64): 2.0*pi * (20.0 * exp(f0)) / 44100.0
    return 6.283185307179586 * (20.0 * exp((double)f0v)) / 44100.0;
}

// Block-wide inclusive scan of one double per thread (256 threads = 4 waves).
__device__ inline double block_incl_scan(double v, double* wsum) {
    const int lane = threadIdx.x & 63;
    const int wid  = threadIdx.x >> 6;
    #pragma unroll
    for (int off = 1; off < 64; off <<= 1) {
        double u = __shfl_up(v, off, 64);
        if (lane >= off) v += u;
    }
    if (lane == 63) wsum[wid] = v;
    __syncthreads();
    double add = 0.0;
    #pragma unroll
    for (int w = 0; w < 3; ++w)
        if (w < wid) add += wsum[w];
    return v + add;
}

// ---------------------------------------------------------------------------
// K1: per-chunk sums of phase_inc. chunk = row*CPR + cpos (256 elems each).
// ---------------------------------------------------------------------------
__global__ __launch_bounds__(256) void sum_kernel(const float* __restrict__ f0,
                                                  double* __restrict__ csum) {
    __shared__ double wsum[4];
    const size_t i = (size_t)blockIdx.x * 256 + threadIdx.x;
    double incl = block_incl_scan(phase_inc(f0[i]), wsum);
    if (threadIdx.x == 255) csum[blockIdx.x] = incl;
}

// ---------------------------------------------------------------------------
// K2: per-row exclusive scan of the 250 chunk sums -> chunk base phases.
// ---------------------------------------------------------------------------
__global__ __launch_bounds__(256) void base_kernel(const double* __restrict__ csum,
                                                   double* __restrict__ base) {
    __shared__ double wsum[4];
    const int row = blockIdx.x;
    const int t   = threadIdx.x;
    double v = (t < CPR) ? csum[row * CPR + t] : 0.0;
    double incl = block_incl_scan(v, wsum);
    if (t < CPR) base[row * CPR + t] = incl - v;   // exclusive
}

// ---------------------------------------------------------------------------
// K3: recompute inc, local f64 scan, phi = base + local; harmonic bank via
// u = frac(phi/2pi) in f64, then f32 k*u products + v_sin_f32 (revolutions).
// The 1/k output weight cancels the k-growth of the f32 product rounding.
// Fused loudness/mix; per-row |max| via one atomicMax per block.
// ---------------------------------------------------------------------------
__global__ __launch_bounds__(256) void harm_kernel(const float* __restrict__ f0,
                                                   const float* __restrict__ loud,
                                                   const float* __restrict__ mixp,
                                                   const float* __restrict__ noise,
                                                   const double* __restrict__ base,
                                                   float* __restrict__ out,
                                                   unsigned int* __restrict__ rowmax) {
    __shared__ double wsum[4];
    const int chunk = blockIdx.x;
    const int row   = chunk / CPR;
    const size_t i  = (size_t)chunk * 256 + threadIdx.x;

    double incl = block_incl_scan(phase_inc(f0[i]), wsum);
    double phi  = base[chunk] + incl;

    double u = phi * 0.15915494309189535;   // revolutions
    u -= floor(u);                          // [0,1)
    const float uf = (float)u;

    float acc = 0.0f;
    #pragma unroll
    for (int k = 1; k <= NH; ++k) {
        float xk = uf * (float)k;
        xk -= floorf(xk);                              // [0,1) revolutions
        acc = fmaf(__builtin_amdgcn_sinf(xk), 1.0f / (float)k, acc);
    }

    const float L  = loud[i];
    const float ha = acc * L;
    const float na = noise[i] * L;
    const float m  = mixp[i];
    const float a  = m * ha + (1.0f - m) * na;
    out[i] = a;

    // block max(|a|) -> one atomic per row per block
    float v = fabsf(a);
    #pragma unroll
    for (int off = 32; off > 0; off >>= 1)
        v = fmaxf(v, __shfl_down(v, off));
    __shared__ float smax[4];
    if ((threadIdx.x & 63) == 0) smax[threadIdx.x >> 6] = v;
    __syncthreads();
    if (threadIdx.x == 0) {
        float bm = fmaxf(fmaxf(smax[0], smax[1]), fmaxf(smax[2], smax[3]));
        atomicMax(rowmax + row, __float_as_uint(bm));
    }
}

// ---------------------------------------------------------------------------
// K4: normalize by per-row peak. T%4==0 so each float4 stays within a row.
// ---------------------------------------------------------------------------
__global__ __launch_bounds__(256) void norm_kernel(float* __restrict__ out,
                                                   const unsigned int* __restrict__ rowmax) {
    const size_t q = (size_t)blockIdx.x * blockDim.x + threadIdx.x;
    const size_t i = q * 4;
    const int row = (int)(i / TLEN);
    const float denom = __uint_as_float(rowmax[row]) + 1e-6f;
    float4 v = *reinterpret_cast<float4*>(out + i);
    v.x /= denom; v.y /= denom; v.z /= denom; v.w /= denom;
    *reinterpret_cast<float4*>(out + i) = v;
}

extern "C" void kernel_launch(void* const* d_in, const int* in_sizes, int n_in,
                              void* d_out, int out_size, void* d_ws, size_t ws_size,
                              hipStream_t stream) {
    const float* f0    = (const float*)d_in[0];
    const float* loud  = (const float*)d_in[1];
    const float* mixp  = (const float*)d_in[2];
    const float* noise = (const float*)d_in[3];
    float* out = (float*)d_out;

    double* csum = (double*)d_ws;             // 8000 doubles
    double* base = csum + NCHUNK;             // 8000 doubles
    unsigned int* rowmax = (unsigned int*)(base + NCHUNK);  // 32 uints

    hipMemsetAsync(rowmax, 0, NROWS * sizeof(unsigned int), stream);
    sum_kernel <<<NCHUNK, 256, 0, stream>>>(f0, csum);
    base_kernel<<<NROWS,  256, 0, stream>>>(csum, base);
    harm_kernel<<<NCHUNK, 256, 0, stream>>>(f0, loud, mixp, noise, base, out, rowmax);
    norm_kernel<<<2000,   256, 0, stream>>>(out, rowmax);
}

// Round 6
// 160.067 us; speedup vs baseline: 1.0473x; 1.0473x over previous
//
#include <hip/hip_runtime.h>
#include <math.h>

#define NROWS 32
#define TLEN  64000
#define NH    60
#define CPR   250                   // 256-elem chunks per row
#define NCHUNK (NROWS * CPR)        // 8000

// inc_i = exp(f0_i) * C, C = 2*pi*20/44100 (f64 compile-time fold).
// f32 expf suffices: per-inc rel err ~1e-7 random-walks to ~2e-7 rad total.
#define INC_C (6.283185307179586 * 20.0 / 44100.0)

__device__ inline double wave_incl_scan(double v) {
    const int lane = threadIdx.x & 63;
    #pragma unroll
    for (int off = 1; off < 64; off <<= 1) {
        double u = __shfl_up(v, off, 64);
        if (lane >= off) v += u;
    }
    return v;
}

// ---------------------------------------------------------------------------
// K1: per-chunk (256-elem) sums of phase increments. One wave per chunk,
// float4 per lane, f64 wave reduction. No LDS, no syncthreads.
// ---------------------------------------------------------------------------
__global__ __launch_bounds__(256) void red_kernel(const float* __restrict__ f0,
                                                  double* __restrict__ csum) {
    const int wid = threadIdx.x >> 6, lane = threadIdx.x & 63;
    const int chunk = blockIdx.x * 4 + wid;
    const float4 v = *reinterpret_cast<const float4*>(f0 + (size_t)chunk * 256 + lane * 4);
    double t = ((double)expf(v.x) + (double)expf(v.y) +
                (double)expf(v.z) + (double)expf(v.w)) * INC_C;
    #pragma unroll
    for (int off = 32; off; off >>= 1) t += __shfl_xor(t, off, 64);
    if (lane == 0) csum[chunk] = t;
}

// ---------------------------------------------------------------------------
// K2: per-row exclusive scan of the 250 chunk sums -> chunk base phases.
// ---------------------------------------------------------------------------
__global__ __launch_bounds__(256) void base_kernel(const double* __restrict__ csum,
                                                   double* __restrict__ base) {
    __shared__ double wsum[4];
    const int row = blockIdx.x;
    const int t   = threadIdx.x;
    const int lane = t & 63, wid = t >> 6;
    double v = (t < CPR) ? csum[row * CPR + t] : 0.0;
    double s = v;
    #pragma unroll
    for (int off = 1; off < 64; off <<= 1) {
        double u = __shfl_up(s, off, 64);
        if (lane >= off) s += u;
    }
    if (lane == 63) wsum[wid] = s;
    __syncthreads();
    double add = 0.0;
    #pragma unroll
    for (int w = 0; w < 3; ++w)
        if (w < wid) add += wsum[w];
    s += add;
    if (t < CPR) base[row * CPR + t] = s - v;   // exclusive
}

// ---------------------------------------------------------------------------
// K3: one wave per chunk, 4 samples per lane. f32 expf -> f64 scan -> phase;
// harmonic bank via Chebyshev recurrence s_{k+1} = 2c*s_k - s_{k-1}
// (2 trans + ~118 fma per sample, 1/k weights constant-folded by unroll;
// 4 independent chains per lane for ILP). Fused mix + per-row |max|.
// ---------------------------------------------------------------------------
__global__ __launch_bounds__(256) void harm_kernel(const float* __restrict__ f0,
                                                   const float* __restrict__ loud,
                                                   const float* __restrict__ mixp,
                                                   const float* __restrict__ noise,
                                                   const double* __restrict__ base,
                                                   float* __restrict__ out,
                                                   unsigned int* __restrict__ rowmax) {
    const int wid = threadIdx.x >> 6, lane = threadIdx.x & 63;
    const int chunk = blockIdx.x * 4 + wid;
    const int row   = chunk / CPR;
    const size_t i0 = (size_t)chunk * 256 + (size_t)lane * 4;

    const float4 f = *reinterpret_cast<const float4*>(f0 + i0);
    double p[4];
    p[0] = (double)expf(f.x) * INC_C;
    p[1] = p[0] + (double)expf(f.y) * INC_C;
    p[2] = p[1] + (double)expf(f.z) * INC_C;
    p[3] = p[2] + (double)expf(f.w) * INC_C;
    const double t = p[3];
    const double start = base[chunk] + (wave_incl_scan(t) - t);

    float sk[4], skm1[4], c2[4], acc[4];
    #pragma unroll
    for (int j = 0; j < 4; ++j) {
        double u = (start + p[j]) * 0.15915494309189535;  // revolutions
        u -= floor(u);                                    // [0,1)
        const float uf = (float)u;
        const float s1 = __builtin_amdgcn_sinf(uf);       // v_sin_f32 (rev input)
        c2[j]   = 2.0f * __builtin_amdgcn_cosf(uf);       // v_cos_f32
        sk[j]   = s1;
        skm1[j] = 0.0f;
        acc[j]  = s1;                                     // k=1, weight 1
    }
    #pragma unroll
    for (int k = 2; k <= NH; ++k) {
        #pragma unroll
        for (int j = 0; j < 4; ++j) {
            const float s1 = fmaf(c2[j], sk[j], -skm1[j]);
            skm1[j] = sk[j];
            sk[j]   = s1;
            acc[j]  = fmaf(s1, 1.0f / (float)k, acc[j]);  // 1/k folded
        }
    }

    const float4 L = *reinterpret_cast<const float4*>(loud  + i0);
    const float4 M = *reinterpret_cast<const float4*>(mixp  + i0);
    const float4 N = *reinterpret_cast<const float4*>(noise + i0);
    float4 a;
    a.x = M.x * (acc[0] * L.x) + (1.0f - M.x) * (N.x * L.x);
    a.y = M.y * (acc[1] * L.y) + (1.0f - M.y) * (N.y * L.y);
    a.z = M.z * (acc[2] * L.z) + (1.0f - M.z) * (N.z * L.z);
    a.w = M.w * (acc[3] * L.w) + (1.0f - M.w) * (N.w * L.w);
    *reinterpret_cast<float4*>(out + i0) = a;

    float v = fmaxf(fmaxf(fabsf(a.x), fabsf(a.y)), fmaxf(fabsf(a.z), fabsf(a.w)));
    #pragma unroll
    for (int off = 32; off; off >>= 1)
        v = fmaxf(v, __shfl_xor(v, off, 64));
    if (lane == 0) atomicMax(rowmax + row, __float_as_uint(v));
}

// ---------------------------------------------------------------------------
// K4: normalize by per-row peak (each wave sits fully inside one row).
// ---------------------------------------------------------------------------
__global__ __launch_bounds__(256) void norm_kernel(float* __restrict__ out,
                                                   const unsigned int* __restrict__ rowmax) {
    const size_t q = (size_t)blockIdx.x * blockDim.x + threadIdx.x;
    const size_t i = q * 4;
    const int row = (int)(i / TLEN);
    const float denom = __uint_as_float(rowmax[row]) + 1e-6f;
    float4 v = *reinterpret_cast<float4*>(out + i);
    v.x /= denom; v.y /= denom; v.z /= denom; v.w /= denom;
    *reinterpret_cast<float4*>(out + i) = v;
}

extern "C" void kernel_launch(void* const* d_in, const int* in_sizes, int n_in,
                              void* d_out, int out_size, void* d_ws, size_t ws_size,
                              hipStream_t stream) {
    const float* f0    = (const float*)d_in[0];
    const float* loud  = (const float*)d_in[1];
    const float* mixp  = (const float*)d_in[2];
    const float* noise = (const float*)d_in[3];
    float* out = (float*)d_out;

    double* csum = (double*)d_ws;                           // 8000 doubles
    double* base = csum + NCHUNK;                           // 8000 doubles
    unsigned int* rowmax = (unsigned int*)(base + NCHUNK);  // 32 uints

    hipMemsetAsync(rowmax, 0, NROWS * sizeof(unsigned int), stream);
    red_kernel <<<NCHUNK / 4, 256, 0, stream>>>(f0, csum);
    base_kernel<<<NROWS,      256, 0, stream>>>(csum, base);
    harm_kernel<<<NCHUNK / 4, 256, 0, stream>>>(f0, loud, mixp, noise, base, out, rowmax);
    norm_kernel<<<2000,       256, 0, stream>>>(out, rowmax);
}

// Round 11
// 92.722 us; speedup vs baseline: 1.8080x; 1.7263x over previous
//
#include <hip/hip_runtime.h>
#include <math.h>

#define NROWS 32
#define TLEN  64000
#define NH    60
#define CPR   250                   // 256-elem chunks per row
#define NCHUNK (NROWS * CPR)        // 8000

// Increment in REVOLUTIONS: inc = exp(f0) * 20/44100. All hot-path math is
// f32 in revolutions; v_sin_f32/v_cos_f32 take revolutions natively.
#define C_REV (20.0f / 44100.0f)

// ---------------------------------------------------------------------------
// K1: per-chunk (256-elem) sums of increments (revolutions, f32).
// One wave per chunk, float4 per lane, f32 shfl reduce. No LDS, no f64.
// ---------------------------------------------------------------------------
__global__ __launch_bounds__(256) void red_kernel(const float* __restrict__ f0,
                                                  float* __restrict__ csum) {
    const int wid = threadIdx.x >> 6, lane = threadIdx.x & 63;
    const int chunk = blockIdx.x * 4 + wid;
    const float4 v = *reinterpret_cast<const float4*>(f0 + (size_t)chunk * 256 + lane * 4);
    float t = (__expf(v.x) + __expf(v.y) + __expf(v.z) + __expf(v.w)) * C_REV;
    #pragma unroll
    for (int off = 32; off; off >>= 1) t += __shfl_xor(t, off, 64);
    if (lane == 0) csum[chunk] = t;
}

// ---------------------------------------------------------------------------
// K2: per-row f64 exclusive scan of the 250 chunk sums; reduce mod 1 and
// store the chunk base phase as f32 in [0,1) revolutions. Tiny (32 blocks).
// ---------------------------------------------------------------------------
__global__ __launch_bounds__(256) void base_kernel(const float* __restrict__ csum,
                                                   float* __restrict__ ubase) {
    __shared__ double wsum[4];
    const int row = blockIdx.x;
    const int t   = threadIdx.x;
    const int lane = t & 63, wid = t >> 6;
    double v = (t < CPR) ? (double)csum[row * CPR + t] : 0.0;
    double s = v;
    #pragma unroll
    for (int off = 1; off < 64; off <<= 1) {
        double u = __shfl_up(s, off, 64);
        if (lane >= off) s += u;
    }
    if (lane == 63) wsum[wid] = s;
    __syncthreads();
    double add = 0.0;
    #pragma unroll
    for (int w = 0; w < 3; ++w)
        if (w < wid) add += wsum[w];
    s += add;
    double e = s - v;                      // exclusive prefix (revolutions)
    e -= floor(e);                         // [0,1)
    if (t < CPR) ubase[row * CPR + t] = (float)e;
}

// ---------------------------------------------------------------------------
// K3: one wave per chunk, 4 samples per lane, pure f32. __expf increments,
// f32 wave scan, u = v_fract(ubase + prefix); harmonic bank via Chebyshev
// recurrence (2 trans + ~118 FMA per sample, 4 independent chains for ILP).
// Per-wave |max| -> plain store (NO atomics).
// ---------------------------------------------------------------------------
__global__ __launch_bounds__(256) void harm_kernel(const float* __restrict__ f0,
                                                   const float* __restrict__ loud,
                                                   const float* __restrict__ mixp,
                                                   const float* __restrict__ noise,
                                                   const float* __restrict__ ubase,
                                                   float* __restrict__ out,
                                                   float* __restrict__ wavemax) {
    const int wid = threadIdx.x >> 6, lane = threadIdx.x & 63;
    const int chunk = blockIdx.x * 4 + wid;
    const size_t i0 = (size_t)chunk * 256 + (size_t)lane * 4;

    const float4 f = *reinterpret_cast<const float4*>(f0 + i0);
    float p0 = __expf(f.x) * C_REV;
    float p1 = p0 + __expf(f.y) * C_REV;
    float p2 = p1 + __expf(f.z) * C_REV;
    float p3 = p2 + __expf(f.w) * C_REV;

    // f32 wave inclusive scan of lane totals
    float s = p3;
    #pragma unroll
    for (int off = 1; off < 64; off <<= 1) {
        float u = __shfl_up(s, off, 64);
        if (lane >= off) s += u;
    }
    const float start = ubase[chunk] + (s - p3);   // [0,~1.6)

    float sk[4], skm1[4], c2[4], acc[4];
    const float pj[4] = {p0, p1, p2, p3};
    #pragma unroll
    for (int j = 0; j < 4; ++j) {
        float u = start + pj[j];
        u -= floorf(u);                                // v_fract
        const float s1 = __builtin_amdgcn_sinf(u);     // sin(2*pi*u)
        c2[j]   = 2.0f * __builtin_amdgcn_cosf(u);
        sk[j]   = s1;
        skm1[j] = 0.0f;
        acc[j]  = s1;                                  // k=1
    }
    #pragma unroll
    for (int k = 2; k <= NH; ++k) {
        #pragma unroll
        for (int j = 0; j < 4; ++j) {
            const float s1 = fmaf(c2[j], sk[j], -skm1[j]);
            skm1[j] = sk[j];
            sk[j]   = s1;
            acc[j]  = fmaf(s1, 1.0f / (float)k, acc[j]);
        }
    }

    const float4 L = *reinterpret_cast<const float4*>(loud  + i0);
    const float4 M = *reinterpret_cast<const float4*>(mixp  + i0);
    const float4 N = *reinterpret_cast<const float4*>(noise + i0);
    float4 a;
    a.x = M.x * (acc[0] * L.x) + (1.0f - M.x) * (N.x * L.x);
    a.y = M.y * (acc[1] * L.y) + (1.0f - M.y) * (N.y * L.y);
    a.z = M.z * (acc[2] * L.z) + (1.0f - M.z) * (N.z * L.z);
    a.w = M.w * (acc[3] * L.w) + (1.0f - M.w) * (N.w * L.w);
    *reinterpret_cast<float4*>(out + i0) = a;

    float v = fmaxf(fmaxf(fabsf(a.x), fabsf(a.y)), fmaxf(fabsf(a.z), fabsf(a.w)));
    #pragma unroll
    for (int off = 32; off; off >>= 1)
        v = fmaxf(v, __shfl_xor(v, off, 64));
    if (lane == 0) wavemax[chunk] = v;                 // plain store, no atomic
}

// ---------------------------------------------------------------------------
// K4: reduce 250 wave-maxes per row -> rowmax. 32 blocks x 64 lanes.
// ---------------------------------------------------------------------------
__global__ __launch_bounds__(64) void maxred_kernel(const float* __restrict__ wavemax,
                                                    float* __restrict__ rowmax) {
    const int row = blockIdx.x, lane = threadIdx.x;
    float v = 0.0f;
    #pragma unroll
    for (int c = 0; c < 4; ++c) {
        const int idx = lane + c * 64;
        if (idx < CPR) v = fmaxf(v, wavemax[row * CPR + idx]);
    }
    #pragma unroll
    for (int off = 32; off; off >>= 1)
        v = fmaxf(v, __shfl_xor(v, off, 64));
    if (lane == 0) rowmax[row] = v;
}

// ---------------------------------------------------------------------------
// K5: normalize by per-row peak.
// ---------------------------------------------------------------------------
__global__ __launch_bounds__(256) void norm_kernel(float* __restrict__ out,
                                                   const float* __restrict__ rowmax) {
    const size_t q = (size_t)blockIdx.x * blockDim.x + threadIdx.x;
    const size_t i = q * 4;
    const int row = (int)(i / TLEN);
    const float denom = rowmax[row] + 1e-6f;
    float4 v = *reinterpret_cast<float4*>(out + i);
    v.x /= denom; v.y /= denom; v.z /= denom; v.w /= denom;
    *reinterpret_cast<float4*>(out + i) = v;
}

extern "C" void kernel_launch(void* const* d_in, const int* in_sizes, int n_in,
                              void* d_out, int out_size, void* d_ws, size_t ws_size,
                              hipStream_t stream) {
    const float* f0    = (const float*)d_in[0];
    const float* loud  = (const float*)d_in[1];
    const float* mixp  = (const float*)d_in[2];
    const float* noise = (const float*)d_in[3];
    float* out = (float*)d_out;

    float* csum    = (float*)d_ws;            // 8000 f32
    float* ubase   = csum + NCHUNK;           // 8000 f32
    float* wavemax = ubase + NCHUNK;          // 8000 f32
    float* rowmax  = wavemax + NCHUNK;        // 32 f32

    red_kernel   <<<NCHUNK / 4, 256, 0, stream>>>(f0, csum);
    base_kernel  <<<NROWS,      256, 0, stream>>>(csum, ubase);
    harm_kernel  <<<NCHUNK / 4, 256, 0, stream>>>(f0, loud, mixp, noise, ubase, out, wavemax);
    maxred_kernel<<<NROWS,      64,  0, stream>>>(wavemax, rowmax);
    norm_kernel  <<<2000,       256, 0, stream>>>(out, rowmax);
}

// Round 14
// 91.197 us; speedup vs baseline: 1.8382x; 1.0167x over previous
//
#include <hip/hip_runtime.h>
#include <math.h>

#define NROWS 32
#define TLEN  64000
#define NH    60
#define CPR   250                   // 256-elem chunks per row
#define NCHUNK (NROWS * CPR)        // 8000

// Increment in REVOLUTIONS: inc = exp(f0) * 20/44100. All hot-path math is
// f32 in revolutions; v_sin_f32/v_cos_f32 take revolutions natively.
#define C_REV (20.0f / 44100.0f)

// ---------------------------------------------------------------------------
// K1: per-chunk (256-elem) sums of increments (revolutions, f32).
// One wave per chunk, float4 per lane, f32 shfl reduce. No LDS, no f64.
// ---------------------------------------------------------------------------
__global__ __launch_bounds__(256) void red_kernel(const float* __restrict__ f0,
                                                  float* __restrict__ csum) {
    const int wid = threadIdx.x >> 6, lane = threadIdx.x & 63;
    const int chunk = blockIdx.x * 4 + wid;
    const float4 v = *reinterpret_cast<const float4*>(f0 + (size_t)chunk * 256 + lane * 4);
    float t = (__expf(v.x) + __expf(v.y) + __expf(v.z) + __expf(v.w)) * C_REV;
    #pragma unroll
    for (int off = 32; off; off >>= 1) t += __shfl_xor(t, off, 64);
    if (lane == 0) csum[chunk] = t;
}

// ---------------------------------------------------------------------------
// K2: fused base+harm. Per wave (one 256-sample chunk):
//   (a) self-base: f64 butterfly-sum of this row's csum[0..cpos) (L2-resident,
//       4 masked loads/lane), frac -> f32 start phase in [0,1) revolutions.
//   (b) __expf increments, f32 wave scan, u = v_fract(start + prefix).
//   (c) harmonic bank via Chebyshev recurrence s_{k+1} = 2c*s_k - s_{k-1}
//       (2 trans + ~118 FMA per sample, 4 independent chains for ILP).
//   (d) fused loudness/mix; per-wave |max| -> plain coalesced store.
// ---------------------------------------------------------------------------
__global__ __launch_bounds__(256) void harm_kernel(const float* __restrict__ f0,
                                                   const float* __restrict__ loud,
                                                   const float* __restrict__ mixp,
                                                   const float* __restrict__ noise,
                                                   const float* __restrict__ csum,
                                                   float* __restrict__ out,
                                                   float* __restrict__ wavemax) {
    const int wid = threadIdx.x >> 6, lane = threadIdx.x & 63;
    const int chunk = blockIdx.x * 4 + wid;
    const int row   = chunk / CPR;
    const int cpos  = chunk - row * CPR;
    const size_t i0 = (size_t)chunk * 256 + (size_t)lane * 4;

    // (a) exclusive prefix of chunk sums for this row, in f64
    double b = 0.0;
    #pragma unroll
    for (int c = 0; c < 4; ++c) {
        const int idx = lane + c * 64;
        if (idx < cpos) b += (double)csum[row * CPR + idx];
    }
    #pragma unroll
    for (int off = 32; off; off >>= 1) b += __shfl_xor(b, off, 64);
    b -= floor(b);                                 // [0,1) revolutions
    const float start0 = (float)b;

    // (b) within-chunk increments + f32 wave scan
    const float4 f = *reinterpret_cast<const float4*>(f0 + i0);
    float p0 = __expf(f.x) * C_REV;
    float p1 = p0 + __expf(f.y) * C_REV;
    float p2 = p1 + __expf(f.z) * C_REV;
    float p3 = p2 + __expf(f.w) * C_REV;

    float s = p3;
    #pragma unroll
    for (int off = 1; off < 64; off <<= 1) {
        float u = __shfl_up(s, off, 64);
        if (lane >= off) s += u;
    }
    const float start = start0 + (s - p3);         // [0,~1.7)

    // (c) harmonic bank
    float sk[4], skm1[4], c2[4], acc[4];
    const float pj[4] = {p0, p1, p2, p3};
    #pragma unroll
    for (int j = 0; j < 4; ++j) {
        float u = start + pj[j];
        u -= floorf(u);                                // v_fract
        const float s1 = __builtin_amdgcn_sinf(u);     // sin(2*pi*u)
        c2[j]   = 2.0f * __builtin_amdgcn_cosf(u);
        sk[j]   = s1;
        skm1[j] = 0.0f;
        acc[j]  = s1;                                  // k=1
    }
    #pragma unroll
    for (int k = 2; k <= NH; ++k) {
        #pragma unroll
        for (int j = 0; j < 4; ++j) {
            const float s1 = fmaf(c2[j], sk[j], -skm1[j]);
            skm1[j] = sk[j];
            sk[j]   = s1;
            acc[j]  = fmaf(s1, 1.0f / (float)k, acc[j]);
        }
    }

    // (d) mix + per-wave max
    const float4 L = *reinterpret_cast<const float4*>(loud  + i0);
    const float4 M = *reinterpret_cast<const float4*>(mixp  + i0);
    const float4 N = *reinterpret_cast<const float4*>(noise + i0);
    float4 a;
    a.x = M.x * (acc[0] * L.x) + (1.0f - M.x) * (N.x * L.x);
    a.y = M.y * (acc[1] * L.y) + (1.0f - M.y) * (N.y * L.y);
    a.z = M.z * (acc[2] * L.z) + (1.0f - M.z) * (N.z * L.z);
    a.w = M.w * (acc[3] * L.w) + (1.0f - M.w) * (N.w * L.w);
    *reinterpret_cast<float4*>(out + i0) = a;

    float v = fmaxf(fmaxf(fabsf(a.x), fabsf(a.y)), fmaxf(fabsf(a.z), fabsf(a.w)));
    #pragma unroll
    for (int off = 32; off; off >>= 1)
        v = fmaxf(v, __shfl_xor(v, off, 64));
    if (lane == 0) wavemax[chunk] = v;                 // plain store, no atomic
}

// ---------------------------------------------------------------------------
// K3: fused maxred+norm. One wave per chunk: butterfly-max of this row's 250
// wave-maxes (L2-resident, 4 masked loads/lane) -> denom; scale 256 samples.
// ---------------------------------------------------------------------------
__global__ __launch_bounds__(64) void norm_kernel(float* __restrict__ out,
                                                  const float* __restrict__ wavemax) {
    const int chunk = blockIdx.x;
    const int row   = chunk / CPR;
    const int lane  = threadIdx.x;

    float m = 0.0f;
    #pragma unroll
    for (int c = 0; c < 4; ++c) {
        const int idx = lane + c * 64;
        if (idx < CPR) m = fmaxf(m, wavemax[row * CPR + idx]);
    }
    #pragma unroll
    for (int off = 32; off; off >>= 1)
        m = fmaxf(m, __shfl_xor(m, off, 64));
    const float denom = m + 1e-6f;

    const size_t i0 = (size_t)chunk * 256 + (size_t)lane * 4;
    float4 v = *reinterpret_cast<float4*>(out + i0);
    v.x /= denom; v.y /= denom; v.z /= denom; v.w /= denom;
    *reinterpret_cast<float4*>(out + i0) = v;
}

extern "C" void kernel_launch(void* const* d_in, const int* in_sizes, int n_in,
                              void* d_out, int out_size, void* d_ws, size_t ws_size,
                              hipStream_t stream) {
    const float* f0    = (const float*)d_in[0];
    const float* loud  = (const float*)d_in[1];
    const float* mixp  = (const float*)d_in[2];
    const float* noise = (const float*)d_in[3];
    float* out = (float*)d_out;

    float* csum    = (float*)d_ws;            // 8000 f32
    float* wavemax = csum + NCHUNK;           // 8000 f32

    red_kernel <<<NCHUNK / 4, 256, 0, stream>>>(f0, csum);
    harm_kernel<<<NCHUNK / 4, 256, 0, stream>>>(f0, loud, mixp, noise, csum, out, wavemax);
    norm_kernel<<<NCHUNK,     64,  0, stream>>>(out, wavemax);
}